// Round 5
// baseline (758.417 us; speedup 1.0000x reference)
//
#include <hip/hip_runtime.h>
#include <stdint.h>

// Problem: TransformerBlock  B=2 N=2048 D=1024 H=16 DH=64 DFF=4096.
// Inputs FLOAT32, output FLOAT32 (reference is all-f32; harness allows 2%-of-max
// error so internals use bf16 MFMA). Round 3/4 A/B-validated the MFMA flash
// attention (bit-identical final error vs independent naive VALU attention).
//
// Pipeline (all on `stream`):
//   1. LN1(x f32) -> h bf16
//   2. qkv = h @ w_qkv^T                 [MFMA gemm NT; W staged f32->bf16]
//   3. RoPE + head-reorder: qr,kr [B,H,N,64], vt [B,H,64,N]   (bf16)
//   4. flash attention (64x64 tiles, online softmax) -> ob [B,N,D] bf16
//   5. x1 = x + ob @ w_o^T               [f32 residual stream]
//   6. LN2(x1) -> h2 bf16
//   7. up  = h2 @ w_up^T + b_up          bf16
//   8. up  = up * silu(h2 @ w_gate^T + b_gate)   [in-place gate epilogue]
//   9. out = x1 + up @ w_out^T + b_out   -> d_out  FLOAT32
//
// ws layout — 64 MB TOTAL:
//   [0,8):   h   (dead after qkv gemm)
//   [8,32):  qkv (dead after rope)   -> then x1 f32 [8,24) + h2 [24,32)
//   [32,40): qr | [40,48): kr | [48,56): vt   (dead after attn)
//   [56,64): ob  (dead after o-proj gemm)
//   [32,64): up  (written after attn buffers die; gate applied in-place)

#define B_ 2
#define N_ 2048
#define D_ 1024
#define H_ 16
#define DFF_ 4096
#define ROWS_ (B_*N_)

typedef unsigned short u16;
typedef short short8 __attribute__((ext_vector_type(8)));
typedef float float4_ __attribute__((ext_vector_type(4)));

#define NEGBIG (-1e30f)

__device__ __forceinline__ float b2f(u16 u) {
  union { unsigned u; float f; } c; c.u = ((unsigned)u) << 16; return c.f;
}
__device__ __forceinline__ u16 f2b(float f) {
  union { float f; unsigned u; } c; c.f = f;
  unsigned x = c.u;
  x += 0x7fffu + ((x >> 16) & 1u);   // round-to-nearest-even
  return (u16)(x >> 16);
}

// ---------------- LayerNorm (one block per row of D=1024), f32 in -> bf16 out
__global__ __launch_bounds__(256) void ln_kernel(const float* __restrict__ xin,
                                                 const float* __restrict__ gamma,
                                                 u16* __restrict__ out) {
  int row = blockIdx.x, t = threadIdx.x;
  float4_ v = *(const float4_*)(xin + (size_t)row * D_ + t * 4);
  float s = 0.f, ss = 0.f;
#pragma unroll
  for (int i = 0; i < 4; i++) { s += v[i]; ss += v[i] * v[i]; }
#pragma unroll
  for (int off = 1; off < 64; off <<= 1) {
    s  += __shfl_xor(s, off, 64);
    ss += __shfl_xor(ss, off, 64);
  }
  __shared__ float red[8];
  if ((t & 63) == 0) { red[t >> 6] = s; red[4 + (t >> 6)] = ss; }
  __syncthreads();
  s  = red[0] + red[1] + red[2] + red[3];
  ss = red[4] + red[5] + red[6] + red[7];
  float mu  = s * (1.f / D_);
  float var = ss * (1.f / D_) - mu * mu;   // biased var (jnp.var default)
  float rs  = rsqrtf(var + 1e-5f);
#pragma unroll
  for (int i = 0; i < 4; i++)
    out[(size_t)row * D_ + t * 4 + i] = f2b((v[i] - mu) * rs * gamma[t * 4 + i]);
}

// ---------------- NT GEMM: C[m,n] = sum_k A[m,k]*W[n,k] (+epilogue) ----------
// A: bf16 (ws buffer). W: f32 input, converted to bf16 during LDS staging.
// 128x128 tile, BK=32, 4 waves, each wave 64x64 via 4x4 mfma_f32_16x16x32_bf16.
// MODE 0: store bf16
// MODE 1: + bias(f32) -> bf16
// MODE 2: + residual(f32 extra) -> f32 out   (o-proj -> x1)
// MODE 3: gate: out = up(extra,bf16) * silu(acc + bias) -> bf16 (extra aliases Cout)
// MODE 4: + bias + residual(f32 extra) -> FLOAT32 out (final)
template <int MODE>
__global__ __launch_bounds__(256) void gemm_nt(const u16* __restrict__ A,
                                               const float* __restrict__ W,
                                               void* Cout,
                                               const float* __restrict__ bias,
                                               const void* extra,
                                               int M, int N, int K) {
  __shared__ __align__(16) u16 sA[128 * 32];
  __shared__ __align__(16) u16 sW[128 * 32];
  int t = threadIdx.x;
  int mbase = blockIdx.y * 128;
  int nbase = blockIdx.x * 128;
  int wave = t >> 6, lane = t & 63;
  int wr = wave >> 1, wc = wave & 1;
  int quad = lane >> 4, l16 = lane & 15;

  float4_ z4 = {0.f, 0.f, 0.f, 0.f};
  float4_ acc[4][4];
#pragma unroll
  for (int i = 0; i < 4; i++)
#pragma unroll
    for (int j = 0; j < 4; j++) acc[i][j] = z4;

  for (int k0 = 0; k0 < K; k0 += 32) {
    __syncthreads();
#pragma unroll
    for (int it = 0; it < 2; it++) {
      int c = t + 256 * it;          // chunk of 8 elems; 512 chunks per tile
      int row = c >> 2, col = (c & 3) << 3;
      ((short8*)sA)[c] = *(const short8*)(A + (size_t)(mbase + row) * K + k0 + col);
      const float* wp = W + (size_t)(nbase + row) * K + k0 + col;
      float4_ w0 = *(const float4_*)wp;
      float4_ w1 = *(const float4_*)(wp + 4);
      short8 pk;
#pragma unroll
      for (int e = 0; e < 4; e++) { pk[e] = (short)f2b(w0[e]); pk[4 + e] = (short)f2b(w1[e]); }
      ((short8*)sW)[c] = pk;
    }
    __syncthreads();
    short8 af[4], bf[4];
#pragma unroll
    for (int i = 0; i < 4; i++)
      af[i] = *(const short8*)(sA + (wr * 64 + i * 16 + l16) * 32 + quad * 8);
#pragma unroll
    for (int j = 0; j < 4; j++)
      bf[j] = *(const short8*)(sW + (wc * 64 + j * 16 + l16) * 32 + quad * 8);
#pragma unroll
    for (int i = 0; i < 4; i++)
#pragma unroll
      for (int j = 0; j < 4; j++)
        acc[i][j] = __builtin_amdgcn_mfma_f32_16x16x32_bf16(af[i], bf[j], acc[i][j], 0, 0, 0);
  }

  // epilogue: C/D layout col=lane&15, row=quad*4+reg  [m89-verified]
#pragma unroll
  for (int i = 0; i < 4; i++) {
#pragma unroll
    for (int r = 0; r < 4; r++) {
      int row = mbase + wr * 64 + i * 16 + quad * 4 + r;
#pragma unroll
      for (int j = 0; j < 4; j++) {
        int col = nbase + wc * 64 + j * 16 + l16;
        size_t idx = (size_t)row * N + col;
        float v = acc[i][j][r];
        if (MODE == 0) {
          ((u16*)Cout)[idx] = f2b(v);
        } else if (MODE == 1) {
          ((u16*)Cout)[idx] = f2b(v + bias[col]);
        } else if (MODE == 2) {
          ((float*)Cout)[idx] = v + ((const float*)extra)[idx];
        } else if (MODE == 3) {
          float gate = v + bias[col];
          float sig = 1.f / (1.f + expf(-gate));
          float upv = b2f(((const u16*)extra)[idx]);   // same idx read-then-write
          ((u16*)Cout)[idx] = f2b(upv * gate * sig);
        } else {
          ((float*)Cout)[idx] = v + bias[col] + ((const float*)extra)[idx];  // f32 final
        }
      }
    }
  }
}

// ---------------- RoPE + head reorder (+ V transpose); freqs f32 ------------
__global__ __launch_bounds__(256) void rope_kernel(const u16* __restrict__ qkv,
                                                   const float* __restrict__ freqs,
                                                   u16* __restrict__ qr,
                                                   u16* __restrict__ kr,
                                                   u16* __restrict__ vt) {
  int idx = blockIdx.x * 256 + threadIdx.x;   // [b(1)|n(11)|h(4)|d2(5)] bits
  int d2 = idx & 31;
  int h  = (idx >> 5) & 15;
  int n  = (idx >> 9) & 2047;
  int b  = idx >> 20;
  float f = freqs[n * 64 + d2];        // freqs[:, d2] == freqs[:, d2+32]
  float c = cosf(f), s = sinf(f);
  size_t base = (size_t)(b * N_ + n) * 3072;
  int hd = h * 64 + d2;
  float q1 = b2f(qkv[base + hd]),        q2 = b2f(qkv[base + hd + 32]);
  float k1 = b2f(qkv[base + 1024 + hd]), k2 = b2f(qkv[base + 1024 + hd + 32]);
  float v1 = b2f(qkv[base + 2048 + hd]), v2 = b2f(qkv[base + 2048 + hd + 32]);
  size_t ro = ((size_t)(b * H_ + h) * N_ + n) * 64 + d2;
  qr[ro]      = f2b(q1 * c - q2 * s);
  qr[ro + 32] = f2b(q2 * c + q1 * s);
  kr[ro]      = f2b(k1 * c - k2 * s);
  kr[ro + 32] = f2b(k2 * c + k1 * s);
  size_t vo = ((size_t)(b * H_ + h) * 64 + d2) * N_ + n;
  vt[vo]           = f2b(v1);
  vt[vo + 32 * N_] = f2b(v2);
}

// ---------------- Flash attention: 64 q-rows per block, 64-key tiles ---------
// A/B-validated vs independent naive VALU attention (rounds 3/4: identical out).
__global__ __launch_bounds__(256) void attn_kernel(const u16* __restrict__ qr,
                                                   const u16* __restrict__ kr,
                                                   const u16* __restrict__ vt,
                                                   u16* __restrict__ obuf) {
  __shared__ __align__(16) u16 sK[64 * 64];        // [key][d]
  __shared__ __align__(16) u16 sV[64 * 64];        // [dh][key]
  __shared__ __align__(16) u16 sP[4][16 * 64];     // per-wave P tile [qi][key]
  int qt = blockIdx.x, bh = blockIdx.y;
  int b = bh >> 4, h = bh & 15;
  int t = threadIdx.x, wave = t >> 6, lane = t & 63;
  int quad = lane >> 4, l16 = lane & 15;
  int qbase = qt * 64;
  const u16* qp = qr + (size_t)bh * N_ * 64;
  const u16* kp = kr + (size_t)bh * N_ * 64;
  const u16* vp = vt + (size_t)bh * 64 * N_;

  // Q fragments stay in registers whole kernel (A-layout: m=l16, k=quad*8+j)
  short8 aq[2];
  int qrow = qbase + wave * 16 + l16;
#pragma unroll
  for (int kk = 0; kk < 2; kk++)
    aq[kk] = *(const short8*)(qp + (size_t)qrow * 64 + kk * 32 + quad * 8);

  float4_ z4 = {0.f, 0.f, 0.f, 0.f};
  float4_ o[4] = {z4, z4, z4, z4};
  float m_r[4] = {NEGBIG, NEGBIG, NEGBIG, NEGBIG};
  float l_r[4] = {0.f, 0.f, 0.f, 0.f};

  for (int kt = 0; kt <= qt; kt++) {
    __syncthreads();
    {
      const u16* src = kp + (size_t)kt * 64 * 64;   // K tile: fully contiguous
#pragma unroll
      for (int it = 0; it < 2; it++) {
        int c = t + 256 * it;
        ((short8*)sK)[c] = *(const short8*)(src + c * 8);
        int row = c >> 3, seg = c & 7;               // V^T tile rows (dh), 64 keys
        ((short8*)sV)[c] = *(const short8*)(vp + (size_t)row * N_ + kt * 64 + seg * 8);
      }
    }
    __syncthreads();

    // S = (Q K^T) * 1/8
    float4_ sf[4];
#pragma unroll
    for (int j = 0; j < 4; j++) {
      short8 bk0 = *(const short8*)(sK + (j * 16 + l16) * 64 + quad * 8);
      short8 bk1 = *(const short8*)(sK + (j * 16 + l16) * 64 + 32 + quad * 8);
      float4_ acc = z4;
      acc = __builtin_amdgcn_mfma_f32_16x16x32_bf16(aq[0], bk0, acc, 0, 0, 0);
      acc = __builtin_amdgcn_mfma_f32_16x16x32_bf16(aq[1], bk1, acc, 0, 0, 0);
      sf[j] = acc;
    }
#pragma unroll
    for (int j = 0; j < 4; j++)
#pragma unroll
      for (int r = 0; r < 4; r++) {
        float sv = sf[j][r] * 0.125f;
        if (kt == qt) {
          int ig = qbase + wave * 16 + quad * 4 + r;
          int jg = kt * 64 + j * 16 + l16;
          if (jg > ig) sv = NEGBIG;                   // causal
        }
        sf[j][r] = sv;
      }

    // online softmax per query row r (row = quad*4+r lives in this quad's 16 lanes)
#pragma unroll
    for (int r = 0; r < 4; r++) {
      float mt = fmaxf(fmaxf(sf[0][r], sf[1][r]), fmaxf(sf[2][r], sf[3][r]));
#pragma unroll
      for (int off = 1; off < 16; off <<= 1) mt = fmaxf(mt, __shfl_xor(mt, off, 64));
      float mn = fmaxf(m_r[r], mt);
      float alpha = expf(m_r[r] - mn);
      float rowsum = 0.f;
#pragma unroll
      for (int j = 0; j < 4; j++) {
        float p = expf(sf[j][r] - mn);
        sf[j][r] = p;
        rowsum += p;
      }
#pragma unroll
      for (int off = 1; off < 16; off <<= 1) rowsum += __shfl_xor(rowsum, off, 64);
      l_r[r] = l_r[r] * alpha + rowsum;
      m_r[r] = mn;
#pragma unroll
      for (int jo = 0; jo < 4; jo++) o[jo][r] *= alpha;
    }

    // P (C-layout) -> LDS -> A-layout, then O += P V
    u16* sPw = sP[wave];
#pragma unroll
    for (int j = 0; j < 4; j++)
#pragma unroll
      for (int r = 0; r < 4; r++)
        sPw[(quad * 4 + r) * 64 + j * 16 + l16] = f2b(sf[j][r]);
    __syncthreads();
    short8 ap[2];
#pragma unroll
    for (int kk = 0; kk < 2; kk++)
      ap[kk] = *(const short8*)(sPw + l16 * 64 + kk * 32 + quad * 8);
#pragma unroll
    for (int jo = 0; jo < 4; jo++)
#pragma unroll
      for (int kk = 0; kk < 2; kk++) {
        short8 bv = *(const short8*)(sV + (jo * 16 + l16) * 64 + kk * 32 + quad * 8);
        o[jo] = __builtin_amdgcn_mfma_f32_16x16x32_bf16(ap[kk], bv, o[jo], 0, 0, 0);
      }
  }

  // normalize + write o_buf[b, n, h*64+dh]
#pragma unroll
  for (int jo = 0; jo < 4; jo++)
#pragma unroll
    for (int r = 0; r < 4; r++) {
      int n = qbase + wave * 16 + quad * 4 + r;
      int col = h * 64 + jo * 16 + l16;
      obuf[(size_t)(b * N_ + n) * D_ + col] = f2b(o[jo][r] / l_r[r]);
    }
}

extern "C" void kernel_launch(void* const* d_in, const int* in_sizes, int n_in,
                              void* d_out, int out_size, void* d_ws, size_t ws_size,
                              hipStream_t stream) {
  const float* x         = (const float*)d_in[0];
  const float* gamma_pre = (const float*)d_in[1];
  const float* w_qkv     = (const float*)d_in[2];
  const float* w_o       = (const float*)d_in[3];
  const float* gamma_ff  = (const float*)d_in[4];
  const float* w_up      = (const float*)d_in[5];
  const float* b_up      = (const float*)d_in[6];
  const float* w_gate    = (const float*)d_in[7];
  const float* b_gate    = (const float*)d_in[8];
  const float* w_out     = (const float*)d_in[9];
  const float* b_out     = (const float*)d_in[10];
  const float* freqs     = (const float*)d_in[11];
  // d_in[12] = mask, all-True -> no-op in reference; ignored.

  char* ws = (char*)d_ws;
  const size_t MB = 1024 * 1024;
  u16*  h   = (u16*)(ws);              // [0,8)
  u16*  qkv = (u16*)(ws + 8 * MB);     // [8,32)   dead after rope
  u16*  qr  = (u16*)(ws + 32 * MB);    // [32,40)  dead after attn
  u16*  kr  = (u16*)(ws + 40 * MB);    // [40,48)  dead after attn
  u16*  vtb = (u16*)(ws + 48 * MB);    // [48,56)  dead after attn
  u16*  ob  = (u16*)(ws + 56 * MB);    // [56,64)  dead after o-proj
  float* x1 = (float*)(ws + 8 * MB);   // [8,24)   f32, reuses dead qkv
  u16*  h2  = (u16*)(ws + 24 * MB);    // [24,32)  reuses dead qkv tail
  u16*  up  = (u16*)(ws + 32 * MB);    // [32,64)  reuses dead attn buffers
  float* out = (float*)d_out;

  ln_kernel<<<ROWS_, 256, 0, stream>>>(x, gamma_pre, h);
  gemm_nt<0><<<dim3(3072 / 128, ROWS_ / 128), 256, 0, stream>>>(
      h, w_qkv, qkv, nullptr, nullptr, ROWS_, 3072, 1024);
  rope_kernel<<<(B_ * N_ * H_ * 32) / 256, 256, 0, stream>>>(qkv, freqs, qr, kr, vtb);
  attn_kernel<<<dim3(N_ / 64, B_ * H_), 256, 0, stream>>>(qr, kr, vtb, ob);
  gemm_nt<2><<<dim3(1024 / 128, ROWS_ / 128), 256, 0, stream>>>(
      ob, w_o, x1, nullptr, x, ROWS_, 1024, 1024);
  ln_kernel<<<ROWS_, 256, 0, stream>>>(x1, gamma_ff, h2);
  gemm_nt<1><<<dim3(4096 / 128, ROWS_ / 128), 256, 0, stream>>>(
      h2, w_up, up, b_up, nullptr, ROWS_, 4096, 1024);
  gemm_nt<3><<<dim3(4096 / 128, ROWS_ / 128), 256, 0, stream>>>(
      h2, w_gate, up, b_gate, up, ROWS_, 4096, 1024);
  gemm_nt<4><<<dim3(1024 / 128, ROWS_ / 128), 256, 0, stream>>>(
      up, w_out, (void*)out, b_out, x1, ROWS_, 1024, 4096);
}

// Round 6
// 604.370 us; speedup vs baseline: 1.2549x; 1.2549x over previous
//
#include <hip/hip_runtime.h>
#include <stdint.h>

// Problem: TransformerBlock  B=2 N=2048 D=1024 H=16 DH=64 DFF=4096.
// Inputs FLOAT32, output FLOAT32. Internals bf16 MFMA (error budget 0.101).
// Round 6: (1) weights pre-converted to bf16 once, GEMMs use m97-style
// global_load_lds(16B) staging for BOTH operands [fallback to f32-staging
// path if ws_size < 96MB]; (2) attention LDS rows padded 64->72 u16 to kill
// 16-way bank conflicts; (3) causal pairing (qt, 31-qt) per block for
// uniform 33-tile work distribution.
//
// ws layout — 96 MB when wide (64 MB fallback):
//   [0,8):   h   (dead after qkv gemm)
//   [8,32):  qkv (dead after rope)   -> then x1 f32 [8,24) + h2 [24,32)
//   [32,40): qr | [40,48): kr | [48,56): vt   (dead after attn)
//   [56,64): ob  (dead after o-proj gemm)
//   [32,64): up  (written after attn buffers die; gate applied in-place)
//   [64,96): bf16 weights (persistent): qkv 6 | o 2 | up 8 | gate 8 | out 8

#define B_ 2
#define N_ 2048
#define D_ 1024
#define H_ 16
#define DFF_ 4096
#define ROWS_ (B_*N_)

typedef unsigned short u16;
typedef short short8 __attribute__((ext_vector_type(8)));
typedef float float4_ __attribute__((ext_vector_type(4)));

#define NEGBIG (-1e30f)

__device__ __forceinline__ float b2f(u16 u) {
  union { unsigned u; float f; } c; c.u = ((unsigned)u) << 16; return c.f;
}
__device__ __forceinline__ u16 f2b(float f) {
  union { float f; unsigned u; } c; c.f = f;
  unsigned x = c.u;
  x += 0x7fffu + ((x >> 16) & 1u);   // round-to-nearest-even
  return (u16)(x >> 16);
}

// async 16B global -> LDS (lane-dense at wave-uniform base; m97 idiom)
__device__ __forceinline__ void gl_lds16(const u16* g, u16* l) {
  __builtin_amdgcn_global_load_lds(
      (const __attribute__((address_space(1))) unsigned int*)g,
      (__attribute__((address_space(3))) unsigned int*)l, 16, 0, 0);
}

// ---------------- f32 -> bf16 weight conversion (one-time) ------------------
__global__ __launch_bounds__(256) void cvt_kernel(const float* __restrict__ src,
                                                  u16* __restrict__ dst, int n) {
  int i = (blockIdx.x * 256 + threadIdx.x) * 8;
  if (i >= n) return;
  float4_ v0 = *(const float4_*)(src + i);
  float4_ v1 = *(const float4_*)(src + i + 4);
  short8 pk;
#pragma unroll
  for (int e = 0; e < 4; e++) { pk[e] = (short)f2b(v0[e]); pk[4 + e] = (short)f2b(v1[e]); }
  *(short8*)(dst + i) = pk;
}

// ---------------- LayerNorm (one block per row of D=1024), f32 in -> bf16 out
__global__ __launch_bounds__(256) void ln_kernel(const float* __restrict__ xin,
                                                 const float* __restrict__ gamma,
                                                 u16* __restrict__ out) {
  int row = blockIdx.x, t = threadIdx.x;
  float4_ v = *(const float4_*)(xin + (size_t)row * D_ + t * 4);
  float s = 0.f, ss = 0.f;
#pragma unroll
  for (int i = 0; i < 4; i++) { s += v[i]; ss += v[i] * v[i]; }
#pragma unroll
  for (int off = 1; off < 64; off <<= 1) {
    s  += __shfl_xor(s, off, 64);
    ss += __shfl_xor(ss, off, 64);
  }
  __shared__ float red[8];
  if ((t & 63) == 0) { red[t >> 6] = s; red[4 + (t >> 6)] = ss; }
  __syncthreads();
  s  = red[0] + red[1] + red[2] + red[3];
  ss = red[4] + red[5] + red[6] + red[7];
  float mu  = s * (1.f / D_);
  float var = ss * (1.f / D_) - mu * mu;   // biased var (jnp.var default)
  float rs  = rsqrtf(var + 1e-5f);
#pragma unroll
  for (int i = 0; i < 4; i++)
    out[(size_t)row * D_ + t * 4 + i] = f2b((v[i] - mu) * rs * gamma[t * 4 + i]);
}

// ---------------- shared GEMM epilogue --------------------------------------
template <int MODE>
__device__ __forceinline__ void gemm_epilogue(float4_ (&acc)[4][4], void* Cout,
                                              const float* bias, const void* extra,
                                              int mbase, int nbase, int N,
                                              int wr, int wc, int quad, int l16) {
#pragma unroll
  for (int i = 0; i < 4; i++) {
#pragma unroll
    for (int r = 0; r < 4; r++) {
      int row = mbase + wr * 64 + i * 16 + quad * 4 + r;
#pragma unroll
      for (int j = 0; j < 4; j++) {
        int col = nbase + wc * 64 + j * 16 + l16;
        size_t idx = (size_t)row * N + col;
        float v = acc[i][j][r];
        if (MODE == 0) {
          ((u16*)Cout)[idx] = f2b(v);
        } else if (MODE == 1) {
          ((u16*)Cout)[idx] = f2b(v + bias[col]);
        } else if (MODE == 2) {
          ((float*)Cout)[idx] = v + ((const float*)extra)[idx];
        } else if (MODE == 3) {
          float gate = v + bias[col];
          float sig = 1.f / (1.f + expf(-gate));
          float upv = b2f(((const u16*)extra)[idx]);   // same idx read-then-write
          ((u16*)Cout)[idx] = f2b(upv * gate * sig);
        } else {
          ((float*)Cout)[idx] = v + bias[col] + ((const float*)extra)[idx];  // f32 final
        }
      }
    }
  }
}

// ---------------- NT GEMM, both operands bf16, global_load_lds staging ------
// C[m,n] = sum_k A[m,k]*W[n,k]. 128x128 tile, BK=32, 4 waves, 4x4 16x16x32.
template <int MODE>
__global__ __launch_bounds__(256) void gemm_bb(const u16* __restrict__ A,
                                               const u16* __restrict__ W,
                                               void* Cout,
                                               const float* __restrict__ bias,
                                               const void* extra,
                                               int M, int N, int K) {
  __shared__ __align__(16) u16 sA[128 * 32];
  __shared__ __align__(16) u16 sW[128 * 32];
  int t = threadIdx.x;
  int mbase = blockIdx.y * 128;
  int nbase = blockIdx.x * 128;
  int wave = t >> 6, lane = t & 63;
  int wr = wave >> 1, wc = wave & 1;
  int quad = lane >> 4, l16 = lane & 15;

  float4_ z4 = {0.f, 0.f, 0.f, 0.f};
  float4_ acc[4][4];
#pragma unroll
  for (int i = 0; i < 4; i++)
#pragma unroll
    for (int j = 0; j < 4; j++) acc[i][j] = z4;

  for (int k0 = 0; k0 < K; k0 += 32) {
    __syncthreads();
    // 512 chunks of 16B per operand tile; wave w stages chunks [w*128, w*128+128)
#pragma unroll
    for (int it = 0; it < 2; it++) {
      int c = wave * 128 + it * 64 + lane;        // lane-dense within wave
      int row = c >> 2, col = (c & 3) << 3;
      gl_lds16(A + (size_t)(mbase + row) * K + k0 + col, sA + (size_t)(wave * 128 + it * 64) * 8);
      gl_lds16(W + (size_t)(nbase + row) * K + k0 + col, sW + (size_t)(wave * 128 + it * 64) * 8);
    }
    __syncthreads();
    short8 af[4], bf[4];
#pragma unroll
    for (int i = 0; i < 4; i++)
      af[i] = *(const short8*)(sA + (wr * 64 + i * 16 + l16) * 32 + quad * 8);
#pragma unroll
    for (int j = 0; j < 4; j++)
      bf[j] = *(const short8*)(sW + (wc * 64 + j * 16 + l16) * 32 + quad * 8);
#pragma unroll
    for (int i = 0; i < 4; i++)
#pragma unroll
      for (int j = 0; j < 4; j++)
        acc[i][j] = __builtin_amdgcn_mfma_f32_16x16x32_bf16(af[i], bf[j], acc[i][j], 0, 0, 0);
  }
  gemm_epilogue<MODE>(acc, Cout, bias, extra, mbase, nbase, N, wr, wc, quad, l16);
}

// ---------------- NT GEMM fallback: W f32, converted during staging ---------
template <int MODE>
__global__ __launch_bounds__(256) void gemm_nt(const u16* __restrict__ A,
                                               const float* __restrict__ W,
                                               void* Cout,
                                               const float* __restrict__ bias,
                                               const void* extra,
                                               int M, int N, int K) {
  __shared__ __align__(16) u16 sA[128 * 32];
  __shared__ __align__(16) u16 sW[128 * 32];
  int t = threadIdx.x;
  int mbase = blockIdx.y * 128;
  int nbase = blockIdx.x * 128;
  int wave = t >> 6, lane = t & 63;
  int wr = wave >> 1, wc = wave & 1;
  int quad = lane >> 4, l16 = lane & 15;

  float4_ z4 = {0.f, 0.f, 0.f, 0.f};
  float4_ acc[4][4];
#pragma unroll
  for (int i = 0; i < 4; i++)
#pragma unroll
    for (int j = 0; j < 4; j++) acc[i][j] = z4;

  for (int k0 = 0; k0 < K; k0 += 32) {
    __syncthreads();
#pragma unroll
    for (int it = 0; it < 2; it++) {
      int c = t + 256 * it;
      int row = c >> 2, col = (c & 3) << 3;
      ((short8*)sA)[c] = *(const short8*)(A + (size_t)(mbase + row) * K + k0 + col);
      const float* wp = W + (size_t)(nbase + row) * K + k0 + col;
      float4_ w0 = *(const float4_*)wp;
      float4_ w1 = *(const float4_*)(wp + 4);
      short8 pk;
#pragma unroll
      for (int e = 0; e < 4; e++) { pk[e] = (short)f2b(w0[e]); pk[4 + e] = (short)f2b(w1[e]); }
      ((short8*)sW)[c] = pk;
    }
    __syncthreads();
    short8 af[4], bf[4];
#pragma unroll
    for (int i = 0; i < 4; i++)
      af[i] = *(const short8*)(sA + (wr * 64 + i * 16 + l16) * 32 + quad * 8);
#pragma unroll
    for (int j = 0; j < 4; j++)
      bf[j] = *(const short8*)(sW + (wc * 64 + j * 16 + l16) * 32 + quad * 8);
#pragma unroll
    for (int i = 0; i < 4; i++)
#pragma unroll
      for (int j = 0; j < 4; j++)
        acc[i][j] = __builtin_amdgcn_mfma_f32_16x16x32_bf16(af[i], bf[j], acc[i][j], 0, 0, 0);
  }
  gemm_epilogue<MODE>(acc, Cout, bias, extra, mbase, nbase, N, wr, wc, quad, l16);
}

// ---------------- RoPE + head reorder (+ V transpose); freqs f32 ------------
__global__ __launch_bounds__(256) void rope_kernel(const u16* __restrict__ qkv,
                                                   const float* __restrict__ freqs,
                                                   u16* __restrict__ qr,
                                                   u16* __restrict__ kr,
                                                   u16* __restrict__ vt) {
  int idx = blockIdx.x * 256 + threadIdx.x;   // [b(1)|n(11)|h(4)|d2(5)] bits
  int d2 = idx & 31;
  int h  = (idx >> 5) & 15;
  int n  = (idx >> 9) & 2047;
  int b  = idx >> 20;
  float f = freqs[n * 64 + d2];        // freqs[:, d2] == freqs[:, d2+32]
  float c = cosf(f), s = sinf(f);
  size_t base = (size_t)(b * N_ + n) * 3072;
  int hd = h * 64 + d2;
  float q1 = b2f(qkv[base + hd]),        q2 = b2f(qkv[base + hd + 32]);
  float k1 = b2f(qkv[base + 1024 + hd]), k2 = b2f(qkv[base + 1024 + hd + 32]);
  float v1 = b2f(qkv[base + 2048 + hd]), v2 = b2f(qkv[base + 2048 + hd + 32]);
  size_t ro = ((size_t)(b * H_ + h) * N_ + n) * 64 + d2;
  qr[ro]      = f2b(q1 * c - q2 * s);
  qr[ro + 32] = f2b(q2 * c + q1 * s);
  kr[ro]      = f2b(k1 * c - k2 * s);
  kr[ro + 32] = f2b(k2 * c + k1 * s);
  size_t vo = ((size_t)(b * H_ + h) * 64 + d2) * N_ + n;
  vt[vo]           = f2b(v1);
  vt[vo + 32 * N_] = f2b(v2);
}

// ---------------- Flash attention -------------------------------------------
// Block processes q-tiles {qp, 31-qp}: uniform 33 k-tiles per block.
// LDS rows padded to 72 u16 (144B = 36 banks) to break 16-way conflicts.
#define LP 72
__global__ __launch_bounds__(256) void attn_kernel(const u16* __restrict__ qr,
                                                   const u16* __restrict__ kr,
                                                   const u16* __restrict__ vt,
                                                   u16* __restrict__ obuf) {
  __shared__ __align__(16) u16 sK[64 * LP];        // [key][d]  (padded)
  __shared__ __align__(16) u16 sV[64 * LP];        // [dh][key] (padded)
  __shared__ __align__(16) u16 sP[4][16 * LP];     // per-wave P tile [qi][key]
  int qp = blockIdx.x, bh = blockIdx.y;
  int b = bh >> 4, h = bh & 15;
  int t = threadIdx.x, wave = t >> 6, lane = t & 63;
  int quad = lane >> 4, l16 = lane & 15;
  const u16* qptr = qr + (size_t)bh * N_ * 64;
  const u16* kp = kr + (size_t)bh * N_ * 64;
  const u16* vp = vt + (size_t)bh * 64 * N_;
  float4_ z4 = {0.f, 0.f, 0.f, 0.f};

  for (int qsel = 0; qsel < 2; qsel++) {
    int qt = qsel ? (N_ / 64 - 1 - qp) : qp;
    int qbase = qt * 64;

    // Q fragments in registers (A-layout: m=l16, k=quad*8+j)
    short8 aq[2];
    int qrow = qbase + wave * 16 + l16;
#pragma unroll
    for (int kk = 0; kk < 2; kk++)
      aq[kk] = *(const short8*)(qptr + (size_t)qrow * 64 + kk * 32 + quad * 8);

    float4_ o[4] = {z4, z4, z4, z4};
    float m_r[4] = {NEGBIG, NEGBIG, NEGBIG, NEGBIG};
    float l_r[4] = {0.f, 0.f, 0.f, 0.f};

    for (int kt = 0; kt <= qt; kt++) {
      __syncthreads();
      {
        const u16* src = kp + (size_t)kt * 64 * 64;   // K tile rows contiguous
#pragma unroll
        for (int it = 0; it < 2; it++) {
          int c = t + 256 * it;
          int row = c >> 3, seg = c & 7;
          *(short8*)(sK + row * LP + seg * 8) = *(const short8*)(src + c * 8);
          *(short8*)(sV + row * LP + seg * 8) =
              *(const short8*)(vp + (size_t)row * N_ + kt * 64 + seg * 8);
        }
      }
      __syncthreads();

      // S = (Q K^T) * 1/8
      float4_ sf[4];
#pragma unroll
      for (int j = 0; j < 4; j++) {
        short8 bk0 = *(const short8*)(sK + (j * 16 + l16) * LP + quad * 8);
        short8 bk1 = *(const short8*)(sK + (j * 16 + l16) * LP + 32 + quad * 8);
        float4_ acc = z4;
        acc = __builtin_amdgcn_mfma_f32_16x16x32_bf16(aq[0], bk0, acc, 0, 0, 0);
        acc = __builtin_amdgcn_mfma_f32_16x16x32_bf16(aq[1], bk1, acc, 0, 0, 0);
        sf[j] = acc;
      }
#pragma unroll
      for (int j = 0; j < 4; j++)
#pragma unroll
        for (int r = 0; r < 4; r++) {
          float sv = sf[j][r] * 0.125f;
          if (kt == qt) {
            int ig = qbase + wave * 16 + quad * 4 + r;
            int jg = kt * 64 + j * 16 + l16;
            if (jg > ig) sv = NEGBIG;                 // causal
          }
          sf[j][r] = sv;
        }

      // online softmax per query row r (row lives in this quad's 16 lanes)
#pragma unroll
      for (int r = 0; r < 4; r++) {
        float mt = fmaxf(fmaxf(sf[0][r], sf[1][r]), fmaxf(sf[2][r], sf[3][r]));
#pragma unroll
        for (int off = 1; off < 16; off <<= 1) mt = fmaxf(mt, __shfl_xor(mt, off, 64));
        float mn = fmaxf(m_r[r], mt);
        float alpha = expf(m_r[r] - mn);
        float rowsum = 0.f;
#pragma unroll
        for (int j = 0; j < 4; j++) {
          float p = expf(sf[j][r] - mn);
          sf[j][r] = p;
          rowsum += p;
        }
#pragma unroll
        for (int off = 1; off < 16; off <<= 1) rowsum += __shfl_xor(rowsum, off, 64);
        l_r[r] = l_r[r] * alpha + rowsum;
        m_r[r] = mn;
#pragma unroll
        for (int jo = 0; jo < 4; jo++) o[jo][r] *= alpha;
      }

      // P (C-layout) -> LDS -> A-layout, then O += P V
      u16* sPw = sP[wave];
#pragma unroll
      for (int j = 0; j < 4; j++)
#pragma unroll
        for (int r = 0; r < 4; r++)
          sPw[(quad * 4 + r) * LP + j * 16 + l16] = f2b(sf[j][r]);
      __syncthreads();
      short8 ap[2];
#pragma unroll
      for (int kk = 0; kk < 2; kk++)
        ap[kk] = *(const short8*)(sPw + l16 * LP + kk * 32 + quad * 8);
#pragma unroll
      for (int jo = 0; jo < 4; jo++)
#pragma unroll
        for (int kk = 0; kk < 2; kk++) {
          short8 bv = *(const short8*)(sV + (jo * 16 + l16) * LP + kk * 32 + quad * 8);
          o[jo] = __builtin_amdgcn_mfma_f32_16x16x32_bf16(ap[kk], bv, o[jo], 0, 0, 0);
        }
    }

    // normalize + write o_buf[b, n, h*64+dh]
#pragma unroll
    for (int jo = 0; jo < 4; jo++)
#pragma unroll
      for (int r = 0; r < 4; r++) {
        int n = qbase + wave * 16 + quad * 4 + r;
        int col = h * 64 + jo * 16 + l16;
        obuf[(size_t)(b * N_ + n) * D_ + col] = f2b(o[jo][r] / l_r[r]);
      }
  }
}

extern "C" void kernel_launch(void* const* d_in, const int* in_sizes, int n_in,
                              void* d_out, int out_size, void* d_ws, size_t ws_size,
                              hipStream_t stream) {
  const float* x         = (const float*)d_in[0];
  const float* gamma_pre = (const float*)d_in[1];
  const float* w_qkv     = (const float*)d_in[2];
  const float* w_o       = (const float*)d_in[3];
  const float* gamma_ff  = (const float*)d_in[4];
  const float* w_up      = (const float*)d_in[5];
  const float* b_up      = (const float*)d_in[6];
  const float* w_gate    = (const float*)d_in[7];
  const float* b_gate    = (const float*)d_in[8];
  const float* w_out     = (const float*)d_in[9];
  const float* b_out     = (const float*)d_in[10];
  const float* freqs     = (const float*)d_in[11];
  // d_in[12] = mask, all-True -> no-op in reference; ignored.

  char* ws = (char*)d_ws;
  const size_t MB = 1024 * 1024;
  u16*  h   = (u16*)(ws);              // [0,8)
  u16*  qkv = (u16*)(ws + 8 * MB);     // [8,32)   dead after rope
  u16*  qr  = (u16*)(ws + 32 * MB);    // [32,40)  dead after attn
  u16*  kr  = (u16*)(ws + 40 * MB);    // [40,48)  dead after attn
  u16*  vtb = (u16*)(ws + 48 * MB);    // [48,56)  dead after attn
  u16*  ob  = (u16*)(ws + 56 * MB);    // [56,64)  dead after o-proj
  float* x1 = (float*)(ws + 8 * MB);   // [8,24)   f32, reuses dead qkv
  u16*  h2  = (u16*)(ws + 24 * MB);    // [24,32)  reuses dead qkv tail
  u16*  up  = (u16*)(ws + 32 * MB);    // [32,64)  reuses dead attn buffers
  float* out = (float*)d_out;

  // bf16 weight cache [64,96) — only if ws is big enough
  bool wide = ws_size >= 96 * MB;
  u16* wb_qkv  = (u16*)(ws + 64 * MB);  // 3M elems -> 6MB
  u16* wb_o    = (u16*)(ws + 70 * MB);  // 1M -> 2MB
  u16* wb_up   = (u16*)(ws + 72 * MB);  // 4M -> 8MB
  u16* wb_gate = (u16*)(ws + 80 * MB);  // 4M -> 8MB
  u16* wb_out  = (u16*)(ws + 88 * MB);  // 4M -> 8MB

  if (wide) {
    cvt_kernel<<<(3 * D_ * D_) / 2048, 256, 0, stream>>>(w_qkv, wb_qkv, 3 * D_ * D_);
    cvt_kernel<<<(D_ * D_) / 2048, 256, 0, stream>>>(w_o, wb_o, D_ * D_);
    cvt_kernel<<<(DFF_ * D_) / 2048, 256, 0, stream>>>(w_up, wb_up, DFF_ * D_);
    cvt_kernel<<<(DFF_ * D_) / 2048, 256, 0, stream>>>(w_gate, wb_gate, DFF_ * D_);
    cvt_kernel<<<(DFF_ * D_) / 2048, 256, 0, stream>>>(w_out, wb_out, D_ * DFF_);
  }

  ln_kernel<<<ROWS_, 256, 0, stream>>>(x, gamma_pre, h);
  if (wide)
    gemm_bb<0><<<dim3(3072 / 128, ROWS_ / 128), 256, 0, stream>>>(
        h, wb_qkv, qkv, nullptr, nullptr, ROWS_, 3072, 1024);
  else
    gemm_nt<0><<<dim3(3072 / 128, ROWS_ / 128), 256, 0, stream>>>(
        h, w_qkv, qkv, nullptr, nullptr, ROWS_, 3072, 1024);
  rope_kernel<<<(B_ * N_ * H_ * 32) / 256, 256, 0, stream>>>(qkv, freqs, qr, kr, vtb);
  attn_kernel<<<dim3(N_ / 128, B_ * H_), 256, 0, stream>>>(qr, kr, vtb, ob);
  if (wide) {
    gemm_bb<2><<<dim3(1024 / 128, ROWS_ / 128), 256, 0, stream>>>(
        ob, wb_o, x1, nullptr, x, ROWS_, 1024, 1024);
    ln_kernel<<<ROWS_, 256, 0, stream>>>(x1, gamma_ff, h2);
    gemm_bb<1><<<dim3(4096 / 128, ROWS_ / 128), 256, 0, stream>>>(
        h2, wb_up, up, b_up, nullptr, ROWS_, 4096, 1024);
    gemm_bb<3><<<dim3(4096 / 128, ROWS_ / 128), 256, 0, stream>>>(
        h2, wb_gate, up, b_gate, up, ROWS_, 4096, 1024);
    gemm_bb<4><<<dim3(1024 / 128, ROWS_ / 128), 256, 0, stream>>>(
        up, wb_out, (void*)out, b_out, x1, ROWS_, 1024, 4096);
  } else {
    gemm_nt<2><<<dim3(1024 / 128, ROWS_ / 128), 256, 0, stream>>>(
        ob, w_o, x1, nullptr, x, ROWS_, 1024, 1024);
    ln_kernel<<<ROWS_, 256, 0, stream>>>(x1, gamma_ff, h2);
    gemm_nt<1><<<dim3(4096 / 128, ROWS_ / 128), 256, 0, stream>>>(
        h2, w_up, up, b_up, nullptr, ROWS_, 4096, 1024);
    gemm_nt<3><<<dim3(4096 / 128, ROWS_ / 128), 256, 0, stream>>>(
        h2, w_gate, up, b_gate, up, ROWS_, 4096, 1024);
    gemm_nt<4><<<dim3(1024 / 128, ROWS_ / 128), 256, 0, stream>>>(
        up, w_out, (void*)out, b_out, x1, ROWS_, 1024, 4096);
  }
}

// Round 7
// 569.440 us; speedup vs baseline: 1.3319x; 1.0613x over previous
//
#include <hip/hip_runtime.h>
#include <stdint.h>

// Problem: TransformerBlock  B=2 N=2048 D=1024 H=16 DH=64 DFF=4096.
// Inputs FLOAT32, output FLOAT32. Internals bf16 MFMA (error budget 0.101).
// Round 7: split-K flash attention (grid 16x32x2 = 1024 blocks, partial
// (o,m,l) + combine kernel), exp2-domain softmax (Q pre-scaled by
// 0.125*log2e in rope), redundant per-wave barrier removed.
//
// ws layout — 96 MB when wide (64 MB fallback):
//   [0,16):  attn partials o_part[2] bf16 (dead region reuse; dead after combine)
//   [16,17): attn partials m,l float2[2][65536]
//   [0,8):   h   (dead after qkv gemm)  [8,32): qkv (dead after rope)
//   x1 f32 [8,24) + h2 [24,32) (written after attn)
//   [32,40): qr | [40,48): kr | [48,56): vt   (dead after attn)
//   [56,64): ob  (dead after o-proj gemm)
//   [32,64): up  (written after attn buffers die; gate applied in-place)
//   [64,96): bf16 weights (persistent): qkv 6 | o 2 | up 8 | gate 8 | out 8

#define B_ 2
#define N_ 2048
#define D_ 1024
#define H_ 16
#define DFF_ 4096
#define ROWS_ (B_*N_)

typedef unsigned short u16;
typedef short short8 __attribute__((ext_vector_type(8)));
typedef float float4_ __attribute__((ext_vector_type(4)));

#define NEGBIG (-1e30f)
#define QSCALE 0.1803368801111204f   // 0.125 * log2(e): softmax in exp2 domain

__device__ __forceinline__ float b2f(u16 u) {
  union { unsigned u; float f; } c; c.u = ((unsigned)u) << 16; return c.f;
}
__device__ __forceinline__ u16 f2b(float f) {
  union { float f; unsigned u; } c; c.f = f;
  unsigned x = c.u;
  x += 0x7fffu + ((x >> 16) & 1u);   // round-to-nearest-even
  return (u16)(x >> 16);
}

// async 16B global -> LDS (lane-dense at wave-uniform base; m97 idiom)
__device__ __forceinline__ void gl_lds16(const u16* g, u16* l) {
  __builtin_amdgcn_global_load_lds(
      (const __attribute__((address_space(1))) unsigned int*)g,
      (__attribute__((address_space(3))) unsigned int*)l, 16, 0, 0);
}

// ---------------- f32 -> bf16 weight conversion (one-time) ------------------
__global__ __launch_bounds__(256) void cvt_kernel(const float* __restrict__ src,
                                                  u16* __restrict__ dst, int n) {
  int i = (blockIdx.x * 256 + threadIdx.x) * 8;
  if (i >= n) return;
  float4_ v0 = *(const float4_*)(src + i);
  float4_ v1 = *(const float4_*)(src + i + 4);
  short8 pk;
#pragma unroll
  for (int e = 0; e < 4; e++) { pk[e] = (short)f2b(v0[e]); pk[4 + e] = (short)f2b(v1[e]); }
  *(short8*)(dst + i) = pk;
}

// ---------------- LayerNorm (one block per row of D=1024), f32 in -> bf16 out
__global__ __launch_bounds__(256) void ln_kernel(const float* __restrict__ xin,
                                                 const float* __restrict__ gamma,
                                                 u16* __restrict__ out) {
  int row = blockIdx.x, t = threadIdx.x;
  float4_ v = *(const float4_*)(xin + (size_t)row * D_ + t * 4);
  float s = 0.f, ss = 0.f;
#pragma unroll
  for (int i = 0; i < 4; i++) { s += v[i]; ss += v[i] * v[i]; }
#pragma unroll
  for (int off = 1; off < 64; off <<= 1) {
    s  += __shfl_xor(s, off, 64);
    ss += __shfl_xor(ss, off, 64);
  }
  __shared__ float red[8];
  if ((t & 63) == 0) { red[t >> 6] = s; red[4 + (t >> 6)] = ss; }
  __syncthreads();
  s  = red[0] + red[1] + red[2] + red[3];
  ss = red[4] + red[5] + red[6] + red[7];
  float mu  = s * (1.f / D_);
  float var = ss * (1.f / D_) - mu * mu;   // biased var (jnp.var default)
  float rs  = rsqrtf(var + 1e-5f);
#pragma unroll
  for (int i = 0; i < 4; i++)
    out[(size_t)row * D_ + t * 4 + i] = f2b((v[i] - mu) * rs * gamma[t * 4 + i]);
}

// ---------------- shared GEMM epilogue --------------------------------------
template <int MODE>
__device__ __forceinline__ void gemm_epilogue(float4_ (&acc)[4][4], void* Cout,
                                              const float* bias, const void* extra,
                                              int mbase, int nbase, int N,
                                              int wr, int wc, int quad, int l16) {
#pragma unroll
  for (int i = 0; i < 4; i++) {
#pragma unroll
    for (int r = 0; r < 4; r++) {
      int row = mbase + wr * 64 + i * 16 + quad * 4 + r;
#pragma unroll
      for (int j = 0; j < 4; j++) {
        int col = nbase + wc * 64 + j * 16 + l16;
        size_t idx = (size_t)row * N + col;
        float v = acc[i][j][r];
        if (MODE == 0) {
          ((u16*)Cout)[idx] = f2b(v);
        } else if (MODE == 1) {
          ((u16*)Cout)[idx] = f2b(v + bias[col]);
        } else if (MODE == 2) {
          ((float*)Cout)[idx] = v + ((const float*)extra)[idx];
        } else if (MODE == 3) {
          float gate = v + bias[col];
          float sig = 1.f / (1.f + expf(-gate));
          float upv = b2f(((const u16*)extra)[idx]);   // same idx read-then-write
          ((u16*)Cout)[idx] = f2b(upv * gate * sig);
        } else {
          ((float*)Cout)[idx] = v + bias[col] + ((const float*)extra)[idx];  // f32 final
        }
      }
    }
  }
}

// ---------------- NT GEMM, both operands bf16, global_load_lds staging ------
template <int MODE>
__global__ __launch_bounds__(256) void gemm_bb(const u16* __restrict__ A,
                                               const u16* __restrict__ W,
                                               void* Cout,
                                               const float* __restrict__ bias,
                                               const void* extra,
                                               int M, int N, int K) {
  __shared__ __align__(16) u16 sA[128 * 32];
  __shared__ __align__(16) u16 sW[128 * 32];
  int t = threadIdx.x;
  int mbase = blockIdx.y * 128;
  int nbase = blockIdx.x * 128;
  int wave = t >> 6, lane = t & 63;
  int wr = wave >> 1, wc = wave & 1;
  int quad = lane >> 4, l16 = lane & 15;

  float4_ z4 = {0.f, 0.f, 0.f, 0.f};
  float4_ acc[4][4];
#pragma unroll
  for (int i = 0; i < 4; i++)
#pragma unroll
    for (int j = 0; j < 4; j++) acc[i][j] = z4;

  for (int k0 = 0; k0 < K; k0 += 32) {
    __syncthreads();
#pragma unroll
    for (int it = 0; it < 2; it++) {
      int c = wave * 128 + it * 64 + lane;        // lane-dense within wave
      int row = c >> 2, col = (c & 3) << 3;
      gl_lds16(A + (size_t)(mbase + row) * K + k0 + col, sA + (size_t)(wave * 128 + it * 64) * 8);
      gl_lds16(W + (size_t)(nbase + row) * K + k0 + col, sW + (size_t)(wave * 128 + it * 64) * 8);
    }
    __syncthreads();
    short8 af[4], bf[4];
#pragma unroll
    for (int i = 0; i < 4; i++)
      af[i] = *(const short8*)(sA + (wr * 64 + i * 16 + l16) * 32 + quad * 8);
#pragma unroll
    for (int j = 0; j < 4; j++)
      bf[j] = *(const short8*)(sW + (wc * 64 + j * 16 + l16) * 32 + quad * 8);
#pragma unroll
    for (int i = 0; i < 4; i++)
#pragma unroll
      for (int j = 0; j < 4; j++)
        acc[i][j] = __builtin_amdgcn_mfma_f32_16x16x32_bf16(af[i], bf[j], acc[i][j], 0, 0, 0);
  }
  gemm_epilogue<MODE>(acc, Cout, bias, extra, mbase, nbase, N, wr, wc, quad, l16);
}

// ---------------- NT GEMM fallback: W f32, converted during staging ---------
template <int MODE>
__global__ __launch_bounds__(256) void gemm_nt(const u16* __restrict__ A,
                                               const float* __restrict__ W,
                                               void* Cout,
                                               const float* __restrict__ bias,
                                               const void* extra,
                                               int M, int N, int K) {
  __shared__ __align__(16) u16 sA[128 * 32];
  __shared__ __align__(16) u16 sW[128 * 32];
  int t = threadIdx.x;
  int mbase = blockIdx.y * 128;
  int nbase = blockIdx.x * 128;
  int wave = t >> 6, lane = t & 63;
  int wr = wave >> 1, wc = wave & 1;
  int quad = lane >> 4, l16 = lane & 15;

  float4_ z4 = {0.f, 0.f, 0.f, 0.f};
  float4_ acc[4][4];
#pragma unroll
  for (int i = 0; i < 4; i++)
#pragma unroll
    for (int j = 0; j < 4; j++) acc[i][j] = z4;

  for (int k0 = 0; k0 < K; k0 += 32) {
    __syncthreads();
#pragma unroll
    for (int it = 0; it < 2; it++) {
      int c = t + 256 * it;
      int row = c >> 2, col = (c & 3) << 3;
      ((short8*)sA)[c] = *(const short8*)(A + (size_t)(mbase + row) * K + k0 + col);
      const float* wp = W + (size_t)(nbase + row) * K + k0 + col;
      float4_ w0 = *(const float4_*)wp;
      float4_ w1 = *(const float4_*)(wp + 4);
      short8 pk;
#pragma unroll
      for (int e = 0; e < 4; e++) { pk[e] = (short)f2b(w0[e]); pk[4 + e] = (short)f2b(w1[e]); }
      ((short8*)sW)[c] = pk;
    }
    __syncthreads();
    short8 af[4], bf[4];
#pragma unroll
    for (int i = 0; i < 4; i++)
      af[i] = *(const short8*)(sA + (wr * 64 + i * 16 + l16) * 32 + quad * 8);
#pragma unroll
    for (int j = 0; j < 4; j++)
      bf[j] = *(const short8*)(sW + (wc * 64 + j * 16 + l16) * 32 + quad * 8);
#pragma unroll
    for (int i = 0; i < 4; i++)
#pragma unroll
      for (int j = 0; j < 4; j++)
        acc[i][j] = __builtin_amdgcn_mfma_f32_16x16x32_bf16(af[i], bf[j], acc[i][j], 0, 0, 0);
  }
  gemm_epilogue<MODE>(acc, Cout, bias, extra, mbase, nbase, N, wr, wc, quad, l16);
}

// ---------------- RoPE + head reorder (+ V transpose); freqs f32 ------------
// Q is pre-scaled by 0.125*log2(e) so attention softmax runs in exp2 domain.
__global__ __launch_bounds__(256) void rope_kernel(const u16* __restrict__ qkv,
                                                   const float* __restrict__ freqs,
                                                   u16* __restrict__ qr,
                                                   u16* __restrict__ kr,
                                                   u16* __restrict__ vt) {
  int idx = blockIdx.x * 256 + threadIdx.x;   // [b(1)|n(11)|h(4)|d2(5)] bits
  int d2 = idx & 31;
  int h  = (idx >> 5) & 15;
  int n  = (idx >> 9) & 2047;
  int b  = idx >> 20;
  float f = freqs[n * 64 + d2];        // freqs[:, d2] == freqs[:, d2+32]
  float c = cosf(f), s = sinf(f);
  size_t base = (size_t)(b * N_ + n) * 3072;
  int hd = h * 64 + d2;
  float q1 = b2f(qkv[base + hd]),        q2 = b2f(qkv[base + hd + 32]);
  float k1 = b2f(qkv[base + 1024 + hd]), k2 = b2f(qkv[base + 1024 + hd + 32]);
  float v1 = b2f(qkv[base + 2048 + hd]), v2 = b2f(qkv[base + 2048 + hd + 32]);
  size_t ro = ((size_t)(b * H_ + h) * N_ + n) * 64 + d2;
  qr[ro]      = f2b((q1 * c - q2 * s) * QSCALE);
  qr[ro + 32] = f2b((q2 * c + q1 * s) * QSCALE);
  kr[ro]      = f2b(k1 * c - k2 * s);
  kr[ro + 32] = f2b(k2 * c + k1 * s);
  size_t vo = ((size_t)(b * H_ + h) * 64 + d2) * N_ + n;
  vt[vo]           = f2b(v1);
  vt[vo + 32 * N_] = f2b(v2);
}

// ---------------- Split-K flash attention ------------------------------------
// grid (16, 32, 2): x = pair {qp, 31-qp}, y = bh, z = key-split.
// Each block writes UNNORMALIZED partial o (bf16) + (m,l) per q-row.
#define LP 72
__global__ __launch_bounds__(256) void attn_kernel(const u16* __restrict__ qr,
                                                   const u16* __restrict__ kr,
                                                   const u16* __restrict__ vt,
                                                   u16* __restrict__ opart,
                                                   float* __restrict__ mlp) {
  __shared__ __align__(16) u16 sK[64 * LP];        // [key][d]  (padded)
  __shared__ __align__(16) u16 sV[64 * LP];        // [dh][key] (padded)
  __shared__ __align__(16) u16 sP[4][16 * LP];     // per-wave P tile [qi][key]
  int qp = blockIdx.x, bh = blockIdx.y, sp = blockIdx.z;
  int t = threadIdx.x, wave = t >> 6, lane = t & 63;
  int quad = lane >> 4, l16 = lane & 15;
  const u16* qptr = qr + (size_t)bh * N_ * 64;
  const u16* kp = kr + (size_t)bh * N_ * 64;
  const u16* vp = vt + (size_t)bh * 64 * N_;
  float4_ z4 = {0.f, 0.f, 0.f, 0.f};

  for (int qsel = 0; qsel < 2; qsel++) {
    int qt = qsel ? (N_ / 64 - 1 - qp) : qp;
    int qbase = qt * 64;
    int ntiles = qt + 1, half = (ntiles + 1) >> 1;
    int ktlo = sp ? half : 0, kthi = sp ? ntiles : half;

    // Q fragments in registers (A-layout: m=l16, k=quad*8+j)
    short8 aq[2];
    int qrow = qbase + wave * 16 + l16;
#pragma unroll
    for (int kk = 0; kk < 2; kk++)
      aq[kk] = *(const short8*)(qptr + (size_t)qrow * 64 + kk * 32 + quad * 8);

    float4_ o[4] = {z4, z4, z4, z4};
    float m_r[4] = {NEGBIG, NEGBIG, NEGBIG, NEGBIG};
    float l_r[4] = {0.f, 0.f, 0.f, 0.f};

    for (int kt = ktlo; kt < kthi; kt++) {
      __syncthreads();
      {
        const u16* src = kp + (size_t)kt * 64 * 64;   // K tile rows contiguous
#pragma unroll
        for (int it = 0; it < 2; it++) {
          int c = t + 256 * it;
          int row = c >> 3, seg = c & 7;
          *(short8*)(sK + row * LP + seg * 8) = *(const short8*)(src + c * 8);
          *(short8*)(sV + row * LP + seg * 8) =
              *(const short8*)(vp + (size_t)row * N_ + kt * 64 + seg * 8);
        }
      }
      __syncthreads();

      // S_log2 = Q K^T  (Q pre-scaled by 0.125*log2e)
      float4_ sf[4];
#pragma unroll
      for (int j = 0; j < 4; j++) {
        short8 bk0 = *(const short8*)(sK + (j * 16 + l16) * LP + quad * 8);
        short8 bk1 = *(const short8*)(sK + (j * 16 + l16) * LP + 32 + quad * 8);
        float4_ acc = z4;
        acc = __builtin_amdgcn_mfma_f32_16x16x32_bf16(aq[0], bk0, acc, 0, 0, 0);
        acc = __builtin_amdgcn_mfma_f32_16x16x32_bf16(aq[1], bk1, acc, 0, 0, 0);
        sf[j] = acc;
      }
      if (kt == qt) {
#pragma unroll
        for (int j = 0; j < 4; j++)
#pragma unroll
          for (int r = 0; r < 4; r++) {
            int ig = qbase + wave * 16 + quad * 4 + r;
            int jg = kt * 64 + j * 16 + l16;
            if (jg > ig) sf[j][r] = NEGBIG;           // causal
          }
      }

      // online softmax (exp2 domain) per query row r
#pragma unroll
      for (int r = 0; r < 4; r++) {
        float mt = fmaxf(fmaxf(sf[0][r], sf[1][r]), fmaxf(sf[2][r], sf[3][r]));
#pragma unroll
        for (int off = 1; off < 16; off <<= 1) mt = fmaxf(mt, __shfl_xor(mt, off, 64));
        float mn = fmaxf(m_r[r], mt);
        float alpha = exp2f(m_r[r] - mn);
        float rowsum = 0.f;
#pragma unroll
        for (int j = 0; j < 4; j++) {
          float p = exp2f(sf[j][r] - mn);
          sf[j][r] = p;
          rowsum += p;
        }
#pragma unroll
        for (int off = 1; off < 16; off <<= 1) rowsum += __shfl_xor(rowsum, off, 64);
        l_r[r] = l_r[r] * alpha + rowsum;
        m_r[r] = mn;
#pragma unroll
        for (int jo = 0; jo < 4; jo++) o[jo][r] *= alpha;
      }

      // P (C-layout) -> LDS -> A-layout (per-wave region: no barrier needed;
      // same-wave DS ops are in-order), then O += P V
      u16* sPw = sP[wave];
#pragma unroll
      for (int j = 0; j < 4; j++)
#pragma unroll
        for (int r = 0; r < 4; r++)
          sPw[(quad * 4 + r) * LP + j * 16 + l16] = f2b(sf[j][r]);
      short8 ap[2];
#pragma unroll
      for (int kk = 0; kk < 2; kk++)
        ap[kk] = *(const short8*)(sPw + l16 * LP + kk * 32 + quad * 8);
#pragma unroll
      for (int jo = 0; jo < 4; jo++)
#pragma unroll
        for (int kk = 0; kk < 2; kk++) {
          short8 bv = *(const short8*)(sV + (jo * 16 + l16) * LP + kk * 32 + quad * 8);
          o[jo] = __builtin_amdgcn_mfma_f32_16x16x32_bf16(ap[kk], bv, o[jo], 0, 0, 0);
        }
    }

    // write partial: opart[sp][bh*N+n][dh] bf16 (unnormalized), ml[sp][bh*N+n]
#pragma unroll
    for (int r = 0; r < 4; r++) {
      int n = qbase + wave * 16 + quad * 4 + r;
      size_t row = (size_t)bh * N_ + n;
      if (l16 == 0) {
        mlp[2 * (sp * (size_t)65536 + row)]     = m_r[r];
        mlp[2 * (sp * (size_t)65536 + row) + 1] = l_r[r];
      }
#pragma unroll
      for (int jo = 0; jo < 4; jo++)
        opart[sp * (size_t)4194304 + row * 64 + jo * 16 + l16] = f2b(o[jo][r]);
    }
  }
}

// ---------------- combine split-K partials -> ob [b,n,h*64+dh] --------------
__global__ __launch_bounds__(256) void attn_combine(const u16* __restrict__ opart,
                                                    const float* __restrict__ mlp,
                                                    u16* __restrict__ obuf) {
  int idx = blockIdx.x * 256 + threadIdx.x;   // 524288 threads: row*8 + seg
  int row = idx >> 3, seg = idx & 7;
  float m0 = mlp[2 * row],                 l0 = mlp[2 * row + 1];
  float m1 = mlp[2 * (65536 + row)],       l1 = mlp[2 * (65536 + row) + 1];
  float mmax = fmaxf(m0, m1);
  float w0 = exp2f(m0 - mmax), w1 = exp2f(m1 - mmax);
  float inv = 1.f / (l0 * w0 + l1 * w1);
  short8 a = *(const short8*)(opart + (size_t)row * 64 + seg * 8);
  short8 b = *(const short8*)(opart + (size_t)4194304 + (size_t)row * 64 + seg * 8);
  short8 r;
#pragma unroll
  for (int e = 0; e < 8; e++)
    r[e] = (short)f2b((b2f((u16)a[e]) * w0 + b2f((u16)b[e]) * w1) * inv);
  int bh = row >> 11, n = row & 2047;
  int bb = bh >> 4, h = bh & 15;
  *(short8*)(obuf + ((size_t)(bb * N_ + n) * D_) + h * 64 + seg * 8) = r;
}

extern "C" void kernel_launch(void* const* d_in, const int* in_sizes, int n_in,
                              void* d_out, int out_size, void* d_ws, size_t ws_size,
                              hipStream_t stream) {
  const float* x         = (const float*)d_in[0];
  const float* gamma_pre = (const float*)d_in[1];
  const float* w_qkv     = (const float*)d_in[2];
  const float* w_o       = (const float*)d_in[3];
  const float* gamma_ff  = (const float*)d_in[4];
  const float* w_up      = (const float*)d_in[5];
  const float* b_up      = (const float*)d_in[6];
  const float* w_gate    = (const float*)d_in[7];
  const float* b_gate    = (const float*)d_in[8];
  const float* w_out     = (const float*)d_in[9];
  const float* b_out     = (const float*)d_in[10];
  const float* freqs     = (const float*)d_in[11];
  // d_in[12] = mask, all-True -> no-op in reference; ignored.

  char* ws = (char*)d_ws;
  const size_t MB = 1024 * 1024;
  u16*  h     = (u16*)(ws);              // [0,8)
  u16*  qkv   = (u16*)(ws + 8 * MB);     // [8,32)   dead after rope
  u16*  qr    = (u16*)(ws + 32 * MB);    // [32,40)  dead after attn
  u16*  kr    = (u16*)(ws + 40 * MB);    // [40,48)  dead after attn
  u16*  vtb   = (u16*)(ws + 48 * MB);    // [48,56)  dead after attn
  u16*  ob    = (u16*)(ws + 56 * MB);    // [56,64)  dead after o-proj
  u16*  opart = (u16*)(ws);              // [0,16)   attn partials (dead qkv/h)
  float* mlb  = (float*)(ws + 16 * MB);  // [16,17)  attn m/l
  float* x1   = (float*)(ws + 8 * MB);   // [8,24)   f32, after combine
  u16*  h2    = (u16*)(ws + 24 * MB);    // [24,32)
  u16*  up    = (u16*)(ws + 32 * MB);    // [32,64)
  float* out  = (float*)d_out;

  // bf16 weight cache [64,96) — only if ws is big enough
  bool wide = ws_size >= 96 * MB;
  u16* wb_qkv  = (u16*)(ws + 64 * MB);
  u16* wb_o    = (u16*)(ws + 70 * MB);
  u16* wb_up   = (u16*)(ws + 72 * MB);
  u16* wb_gate = (u16*)(ws + 80 * MB);
  u16* wb_out  = (u16*)(ws + 88 * MB);

  if (wide) {
    cvt_kernel<<<(3 * D_ * D_) / 2048, 256, 0, stream>>>(w_qkv, wb_qkv, 3 * D_ * D_);
    cvt_kernel<<<(D_ * D_) / 2048, 256, 0, stream>>>(w_o, wb_o, D_ * D_);
    cvt_kernel<<<(DFF_ * D_) / 2048, 256, 0, stream>>>(w_up, wb_up, DFF_ * D_);
    cvt_kernel<<<(DFF_ * D_) / 2048, 256, 0, stream>>>(w_gate, wb_gate, DFF_ * D_);
    cvt_kernel<<<(DFF_ * D_) / 2048, 256, 0, stream>>>(w_out, wb_out, D_ * DFF_);
  }

  ln_kernel<<<ROWS_, 256, 0, stream>>>(x, gamma_pre, h);
  if (wide)
    gemm_bb<0><<<dim3(3072 / 128, ROWS_ / 128), 256, 0, stream>>>(
        h, wb_qkv, qkv, nullptr, nullptr, ROWS_, 3072, 1024);
  else
    gemm_nt<0><<<dim3(3072 / 128, ROWS_ / 128), 256, 0, stream>>>(
        h, w_qkv, qkv, nullptr, nullptr, ROWS_, 3072, 1024);
  rope_kernel<<<(B_ * N_ * H_ * 32) / 256, 256, 0, stream>>>(qkv, freqs, qr, kr, vtb);
  attn_kernel<<<dim3(N_ / 128, B_ * H_, 2), 256, 0, stream>>>(qr, kr, vtb, opart, mlb);
  attn_combine<<<(B_ * H_ * N_ * 8) / 256, 256, 0, stream>>>(opart, mlb, ob);
  if (wide) {
    gemm_bb<2><<<dim3(1024 / 128, ROWS_ / 128), 256, 0, stream>>>(
        ob, wb_o, x1, nullptr, x, ROWS_, 1024, 1024);
    ln_kernel<<<ROWS_, 256, 0, stream>>>(x1, gamma_ff, h2);
    gemm_bb<1><<<dim3(4096 / 128, ROWS_ / 128), 256, 0, stream>>>(
        h2, wb_up, up, b_up, nullptr, ROWS_, 4096, 1024);
    gemm_bb<3><<<dim3(4096 / 128, ROWS_ / 128), 256, 0, stream>>>(
        h2, wb_gate, up, b_gate, up, ROWS_, 4096, 1024);
    gemm_bb<4><<<dim3(1024 / 128, ROWS_ / 128), 256, 0, stream>>>(
        up, wb_out, (void*)out, b_out, x1, ROWS_, 1024, 4096);
  } else {
    gemm_nt<2><<<dim3(1024 / 128, ROWS_ / 128), 256, 0, stream>>>(
        ob, w_o, x1, nullptr, x, ROWS_, 1024, 1024);
    ln_kernel<<<ROWS_, 256, 0, stream>>>(x1, gamma_ff, h2);
    gemm_nt<1><<<dim3(4096 / 128, ROWS_ / 128), 256, 0, stream>>>(
        h2, w_up, up, b_up, nullptr, ROWS_, 4096, 1024);
    gemm_nt<3><<<dim3(4096 / 128, ROWS_ / 128), 256, 0, stream>>>(
        h2, w_gate, up, b_gate, up, ROWS_, 4096, 1024);
    gemm_nt<4><<<dim3(1024 / 128, ROWS_ / 128), 256, 0, stream>>>(
        up, w_out, (void*)out, b_out, x1, ROWS_, 1024, 4096);
  }
}

// Round 8
// 529.872 us; speedup vs baseline: 1.4313x; 1.0747x over previous
//
#include <hip/hip_runtime.h>
#include <stdint.h>

// Problem: TransformerBlock  B=2 N=2048 D=1024 H=16 DH=64 DFF=4096.
// Inputs FLOAT32, output FLOAT32. Internals bf16 MFMA (error budget 0.101).
// Round 8: split-K x2 for the two N=1024 GEMMs (o-proj K=1024, final K=4096)
// whose 256-block grids capped occupancy at 1 block/CU (10.8% measured).
// Partial sums stored bf16 in dead ws regions; vector combine adds
// partials + bias + residual -> f32.
//
// ws layout — 96 MB when wide (64 MB fallback):
//   [0,8):   h (LN1 out; dead after qkv gemm) -> later split-K partial p0
//   [8,32):  qkv (dead after rope) -> x1 f32 [8,24) + h2 [24,32)
//   [24,32): h2 (dead after gate gemm) -> final split-K partial p1
//   [0,16):  attn opart | [16,17): attn m/l   (dead after attn_combine)
//   [32,40): qr | [40,48): kr | [48,56): vt   (dead after attn)
//   [56,64): ob (dead after o-proj)
//   [32,64): up (written after attn buffers die; gate applied in-place)
//   [64,96): bf16 weights: qkv 6 | o 2 | up 8 | gate 8 | out 8

#define B_ 2
#define N_ 2048
#define D_ 1024
#define H_ 16
#define DFF_ 4096
#define ROWS_ (B_*N_)

typedef unsigned short u16;
typedef short short8 __attribute__((ext_vector_type(8)));
typedef float float4_ __attribute__((ext_vector_type(4)));

#define NEGBIG (-1e30f)
#define QSCALE 0.1803368801111204f   // 0.125 * log2(e): softmax in exp2 domain

__device__ __forceinline__ float b2f(u16 u) {
  union { unsigned u; float f; } c; c.u = ((unsigned)u) << 16; return c.f;
}
__device__ __forceinline__ u16 f2b(float f) {
  union { float f; unsigned u; } c; c.f = f;
  unsigned x = c.u;
  x += 0x7fffu + ((x >> 16) & 1u);   // round-to-nearest-even
  return (u16)(x >> 16);
}

// async 16B global -> LDS (lane-dense at wave-uniform base; m97 idiom)
__device__ __forceinline__ void gl_lds16(const u16* g, u16* l) {
  __builtin_amdgcn_global_load_lds(
      (const __attribute__((address_space(1))) unsigned int*)g,
      (__attribute__((address_space(3))) unsigned int*)l, 16, 0, 0);
}

// ---------------- f32 -> bf16 weight conversion (one-time) ------------------
__global__ __launch_bounds__(256) void cvt_kernel(const float* __restrict__ src,
                                                  u16* __restrict__ dst, int n) {
  int i = (blockIdx.x * 256 + threadIdx.x) * 8;
  if (i >= n) return;
  float4_ v0 = *(const float4_*)(src + i);
  float4_ v1 = *(const float4_*)(src + i + 4);
  short8 pk;
#pragma unroll
  for (int e = 0; e < 4; e++) { pk[e] = (short)f2b(v0[e]); pk[4 + e] = (short)f2b(v1[e]); }
  *(short8*)(dst + i) = pk;
}

// ---------------- LayerNorm (one block per row of D=1024), f32 in -> bf16 out
__global__ __launch_bounds__(256) void ln_kernel(const float* __restrict__ xin,
                                                 const float* __restrict__ gamma,
                                                 u16* __restrict__ out) {
  int row = blockIdx.x, t = threadIdx.x;
  float4_ v = *(const float4_*)(xin + (size_t)row * D_ + t * 4);
  float s = 0.f, ss = 0.f;
#pragma unroll
  for (int i = 0; i < 4; i++) { s += v[i]; ss += v[i] * v[i]; }
#pragma unroll
  for (int off = 1; off < 64; off <<= 1) {
    s  += __shfl_xor(s, off, 64);
    ss += __shfl_xor(ss, off, 64);
  }
  __shared__ float red[8];
  if ((t & 63) == 0) { red[t >> 6] = s; red[4 + (t >> 6)] = ss; }
  __syncthreads();
  s  = red[0] + red[1] + red[2] + red[3];
  ss = red[4] + red[5] + red[6] + red[7];
  float mu  = s * (1.f / D_);
  float var = ss * (1.f / D_) - mu * mu;   // biased var (jnp.var default)
  float rs  = rsqrtf(var + 1e-5f);
#pragma unroll
  for (int i = 0; i < 4; i++)
    out[(size_t)row * D_ + t * 4 + i] = f2b((v[i] - mu) * rs * gamma[t * 4 + i]);
}

// ---------------- shared GEMM epilogue --------------------------------------
template <int MODE>
__device__ __forceinline__ void gemm_epilogue(float4_ (&acc)[4][4], void* Cout,
                                              const float* bias, const void* extra,
                                              int mbase, int nbase, int N,
                                              int wr, int wc, int quad, int l16) {
#pragma unroll
  for (int i = 0; i < 4; i++) {
#pragma unroll
    for (int r = 0; r < 4; r++) {
      int row = mbase + wr * 64 + i * 16 + quad * 4 + r;
#pragma unroll
      for (int j = 0; j < 4; j++) {
        int col = nbase + wc * 64 + j * 16 + l16;
        size_t idx = (size_t)row * N + col;
        float v = acc[i][j][r];
        if (MODE == 0) {
          ((u16*)Cout)[idx] = f2b(v);
        } else if (MODE == 1) {
          ((u16*)Cout)[idx] = f2b(v + bias[col]);
        } else if (MODE == 2) {
          ((float*)Cout)[idx] = v + ((const float*)extra)[idx];
        } else if (MODE == 3) {
          float gate = v + bias[col];
          float sig = 1.f / (1.f + expf(-gate));
          float upv = b2f(((const u16*)extra)[idx]);   // same idx read-then-write
          ((u16*)Cout)[idx] = f2b(upv * gate * sig);
        } else {
          ((float*)Cout)[idx] = v + bias[col] + ((const float*)extra)[idx];  // f32 final
        }
      }
    }
  }
}

// ---------------- GEMM core: stage tiles via global_load_lds, MFMA ----------
__device__ __forceinline__ void gemm_core(const u16* A, const u16* W,
                                          float4_ (&acc)[4][4], u16* sA, u16* sW,
                                          int mbase, int nbase, int K,
                                          int klo, int khi,
                                          int wave, int lane, int wr, int wc,
                                          int quad, int l16) {
  for (int k0 = klo; k0 < khi; k0 += 32) {
    __syncthreads();
#pragma unroll
    for (int it = 0; it < 2; it++) {
      int c = wave * 128 + it * 64 + lane;        // lane-dense within wave
      int row = c >> 2, col = (c & 3) << 3;
      gl_lds16(A + (size_t)(mbase + row) * K + k0 + col, sA + (size_t)(wave * 128 + it * 64) * 8);
      gl_lds16(W + (size_t)(nbase + row) * K + k0 + col, sW + (size_t)(wave * 128 + it * 64) * 8);
    }
    __syncthreads();
    short8 af[4], bf[4];
#pragma unroll
    for (int i = 0; i < 4; i++)
      af[i] = *(const short8*)(sA + (wr * 64 + i * 16 + l16) * 32 + quad * 8);
#pragma unroll
    for (int j = 0; j < 4; j++)
      bf[j] = *(const short8*)(sW + (wc * 64 + j * 16 + l16) * 32 + quad * 8);
#pragma unroll
    for (int i = 0; i < 4; i++)
#pragma unroll
      for (int j = 0; j < 4; j++)
        acc[i][j] = __builtin_amdgcn_mfma_f32_16x16x32_bf16(af[i], bf[j], acc[i][j], 0, 0, 0);
  }
}

// ---------------- NT GEMM, both operands bf16 -------------------------------
template <int MODE>
__global__ __launch_bounds__(256) void gemm_bb(const u16* __restrict__ A,
                                               const u16* __restrict__ W,
                                               void* Cout,
                                               const float* __restrict__ bias,
                                               const void* extra,
                                               int M, int N, int K) {
  __shared__ __align__(16) u16 sA[128 * 32];
  __shared__ __align__(16) u16 sW[128 * 32];
  int t = threadIdx.x;
  int mbase = blockIdx.y * 128, nbase = blockIdx.x * 128;
  int wave = t >> 6, lane = t & 63;
  int wr = wave >> 1, wc = wave & 1;
  int quad = lane >> 4, l16 = lane & 15;

  float4_ z4 = {0.f, 0.f, 0.f, 0.f};
  float4_ acc[4][4];
#pragma unroll
  for (int i = 0; i < 4; i++)
#pragma unroll
    for (int j = 0; j < 4; j++) acc[i][j] = z4;

  gemm_core(A, W, acc, sA, sW, mbase, nbase, K, 0, K, wave, lane, wr, wc, quad, l16);
  gemm_epilogue<MODE>(acc, Cout, bias, extra, mbase, nbase, N, wr, wc, quad, l16);
}

// ---------------- split-K (x2) NT GEMM: stores bf16 partials -----------------
__global__ __launch_bounds__(256) void gemm_bb_split(const u16* __restrict__ A,
                                                     const u16* __restrict__ W,
                                                     u16* __restrict__ p0,
                                                     u16* __restrict__ p1,
                                                     int M, int N, int K) {
  __shared__ __align__(16) u16 sA[128 * 32];
  __shared__ __align__(16) u16 sW[128 * 32];
  int t = threadIdx.x;
  int mbase = blockIdx.y * 128, nbase = blockIdx.x * 128;
  int z = blockIdx.z;
  int wave = t >> 6, lane = t & 63;
  int wr = wave >> 1, wc = wave & 1;
  int quad = lane >> 4, l16 = lane & 15;
  int Kh = K >> 1;

  float4_ z4 = {0.f, 0.f, 0.f, 0.f};
  float4_ acc[4][4];
#pragma unroll
  for (int i = 0; i < 4; i++)
#pragma unroll
    for (int j = 0; j < 4; j++) acc[i][j] = z4;

  gemm_core(A, W, acc, sA, sW, mbase, nbase, K, z * Kh, z * Kh + Kh,
            wave, lane, wr, wc, quad, l16);

  u16* P = z ? p1 : p0;
#pragma unroll
  for (int i = 0; i < 4; i++)
#pragma unroll
    for (int r = 0; r < 4; r++) {
      int row = mbase + wr * 64 + i * 16 + quad * 4 + r;
#pragma unroll
      for (int j = 0; j < 4; j++) {
        int col = nbase + wc * 64 + j * 16 + l16;
        P[(size_t)row * N + col] = f2b(acc[i][j][r]);
      }
    }
}

// ---------------- split-K combine: out = p0+p1 [+bias] + resid (f32) --------
__global__ __launch_bounds__(256) void split_combine(const u16* __restrict__ p0,
                                                     const u16* __restrict__ p1,
                                                     const float* __restrict__ bias,
                                                     const float* __restrict__ resid,
                                                     float* __restrict__ out, int N) {
  int idx = (blockIdx.x * 256 + threadIdx.x) * 8;
  int col = idx & (N - 1);
  short8 a = *(const short8*)(p0 + idx);
  short8 b = *(const short8*)(p1 + idx);
  float4_ r0 = *(const float4_*)(resid + idx);
  float4_ r1 = *(const float4_*)(resid + idx + 4);
  float4_ o0, o1;
#pragma unroll
  for (int e = 0; e < 4; e++) {
    float bb0 = bias ? bias[col + e] : 0.f;
    float bb1 = bias ? bias[col + 4 + e] : 0.f;
    o0[e] = b2f((u16)a[e]) + b2f((u16)b[e]) + bb0 + r0[e];
    o1[e] = b2f((u16)a[4 + e]) + b2f((u16)b[4 + e]) + bb1 + r1[e];
  }
  *(float4_*)(out + idx) = o0;
  *(float4_*)(out + idx + 4) = o1;
}

// ---------------- NT GEMM fallback: W f32, converted during staging ---------
template <int MODE>
__global__ __launch_bounds__(256) void gemm_nt(const u16* __restrict__ A,
                                               const float* __restrict__ W,
                                               void* Cout,
                                               const float* __restrict__ bias,
                                               const void* extra,
                                               int M, int N, int K) {
  __shared__ __align__(16) u16 sA[128 * 32];
  __shared__ __align__(16) u16 sW[128 * 32];
  int t = threadIdx.x;
  int mbase = blockIdx.y * 128, nbase = blockIdx.x * 128;
  int wave = t >> 6, lane = t & 63;
  int wr = wave >> 1, wc = wave & 1;
  int quad = lane >> 4, l16 = lane & 15;

  float4_ z4 = {0.f, 0.f, 0.f, 0.f};
  float4_ acc[4][4];
#pragma unroll
  for (int i = 0; i < 4; i++)
#pragma unroll
    for (int j = 0; j < 4; j++) acc[i][j] = z4;

  for (int k0 = 0; k0 < K; k0 += 32) {
    __syncthreads();
#pragma unroll
    for (int it = 0; it < 2; it++) {
      int c = t + 256 * it;
      int row = c >> 2, col = (c & 3) << 3;
      ((short8*)sA)[c] = *(const short8*)(A + (size_t)(mbase + row) * K + k0 + col);
      const float* wp = W + (size_t)(nbase + row) * K + k0 + col;
      float4_ w0 = *(const float4_*)wp;
      float4_ w1 = *(const float4_*)(wp + 4);
      short8 pk;
#pragma unroll
      for (int e = 0; e < 4; e++) { pk[e] = (short)f2b(w0[e]); pk[4 + e] = (short)f2b(w1[e]); }
      ((short8*)sW)[c] = pk;
    }
    __syncthreads();
    short8 af[4], bf[4];
#pragma unroll
    for (int i = 0; i < 4; i++)
      af[i] = *(const short8*)(sA + (wr * 64 + i * 16 + l16) * 32 + quad * 8);
#pragma unroll
    for (int j = 0; j < 4; j++)
      bf[j] = *(const short8*)(sW + (wc * 64 + j * 16 + l16) * 32 + quad * 8);
#pragma unroll
    for (int i = 0; i < 4; i++)
#pragma unroll
      for (int j = 0; j < 4; j++)
        acc[i][j] = __builtin_amdgcn_mfma_f32_16x16x32_bf16(af[i], bf[j], acc[i][j], 0, 0, 0);
  }
  gemm_epilogue<MODE>(acc, Cout, bias, extra, mbase, nbase, N, wr, wc, quad, l16);
}

// ---------------- RoPE + head reorder (+ V transpose); freqs f32 ------------
__global__ __launch_bounds__(256) void rope_kernel(const u16* __restrict__ qkv,
                                                   const float* __restrict__ freqs,
                                                   u16* __restrict__ qr,
                                                   u16* __restrict__ kr,
                                                   u16* __restrict__ vt) {
  int idx = blockIdx.x * 256 + threadIdx.x;   // [b(1)|n(11)|h(4)|d2(5)] bits
  int d2 = idx & 31;
  int h  = (idx >> 5) & 15;
  int n  = (idx >> 9) & 2047;
  int b  = idx >> 20;
  float f = freqs[n * 64 + d2];        // freqs[:, d2] == freqs[:, d2+32]
  float c = cosf(f), s = sinf(f);
  size_t base = (size_t)(b * N_ + n) * 3072;
  int hd = h * 64 + d2;
  float q1 = b2f(qkv[base + hd]),        q2 = b2f(qkv[base + hd + 32]);
  float k1 = b2f(qkv[base + 1024 + hd]), k2 = b2f(qkv[base + 1024 + hd + 32]);
  float v1 = b2f(qkv[base + 2048 + hd]), v2 = b2f(qkv[base + 2048 + hd + 32]);
  size_t ro = ((size_t)(b * H_ + h) * N_ + n) * 64 + d2;
  qr[ro]      = f2b((q1 * c - q2 * s) * QSCALE);
  qr[ro + 32] = f2b((q2 * c + q1 * s) * QSCALE);
  kr[ro]      = f2b(k1 * c - k2 * s);
  kr[ro + 32] = f2b(k2 * c + k1 * s);
  size_t vo = ((size_t)(b * H_ + h) * 64 + d2) * N_ + n;
  vt[vo]           = f2b(v1);
  vt[vo + 32 * N_] = f2b(v2);
}

// ---------------- Split-K flash attention ------------------------------------
#define LP 72
__global__ __launch_bounds__(256) void attn_kernel(const u16* __restrict__ qr,
                                                   const u16* __restrict__ kr,
                                                   const u16* __restrict__ vt,
                                                   u16* __restrict__ opart,
                                                   float* __restrict__ mlp) {
  __shared__ __align__(16) u16 sK[64 * LP];
  __shared__ __align__(16) u16 sV[64 * LP];
  __shared__ __align__(16) u16 sP[4][16 * LP];
  int qp = blockIdx.x, bh = blockIdx.y, sp = blockIdx.z;
  int t = threadIdx.x, wave = t >> 6, lane = t & 63;
  int quad = lane >> 4, l16 = lane & 15;
  const u16* qptr = qr + (size_t)bh * N_ * 64;
  const u16* kp = kr + (size_t)bh * N_ * 64;
  const u16* vp = vt + (size_t)bh * 64 * N_;
  float4_ z4 = {0.f, 0.f, 0.f, 0.f};

  for (int qsel = 0; qsel < 2; qsel++) {
    int qt = qsel ? (N_ / 64 - 1 - qp) : qp;
    int qbase = qt * 64;
    int ntiles = qt + 1, half = (ntiles + 1) >> 1;
    int ktlo = sp ? half : 0, kthi = sp ? ntiles : half;

    short8 aq[2];
    int qrow = qbase + wave * 16 + l16;
#pragma unroll
    for (int kk = 0; kk < 2; kk++)
      aq[kk] = *(const short8*)(qptr + (size_t)qrow * 64 + kk * 32 + quad * 8);

    float4_ o[4] = {z4, z4, z4, z4};
    float m_r[4] = {NEGBIG, NEGBIG, NEGBIG, NEGBIG};
    float l_r[4] = {0.f, 0.f, 0.f, 0.f};

    for (int kt = ktlo; kt < kthi; kt++) {
      __syncthreads();
      {
        const u16* src = kp + (size_t)kt * 64 * 64;
#pragma unroll
        for (int it = 0; it < 2; it++) {
          int c = t + 256 * it;
          int row = c >> 3, seg = c & 7;
          *(short8*)(sK + row * LP + seg * 8) = *(const short8*)(src + c * 8);
          *(short8*)(sV + row * LP + seg * 8) =
              *(const short8*)(vp + (size_t)row * N_ + kt * 64 + seg * 8);
        }
      }
      __syncthreads();

      float4_ sf[4];
#pragma unroll
      for (int j = 0; j < 4; j++) {
        short8 bk0 = *(const short8*)(sK + (j * 16 + l16) * LP + quad * 8);
        short8 bk1 = *(const short8*)(sK + (j * 16 + l16) * LP + 32 + quad * 8);
        float4_ acc = z4;
        acc = __builtin_amdgcn_mfma_f32_16x16x32_bf16(aq[0], bk0, acc, 0, 0, 0);
        acc = __builtin_amdgcn_mfma_f32_16x16x32_bf16(aq[1], bk1, acc, 0, 0, 0);
        sf[j] = acc;
      }
      if (kt == qt) {
#pragma unroll
        for (int j = 0; j < 4; j++)
#pragma unroll
          for (int r = 0; r < 4; r++) {
            int ig = qbase + wave * 16 + quad * 4 + r;
            int jg = kt * 64 + j * 16 + l16;
            if (jg > ig) sf[j][r] = NEGBIG;
          }
      }

#pragma unroll
      for (int r = 0; r < 4; r++) {
        float mt = fmaxf(fmaxf(sf[0][r], sf[1][r]), fmaxf(sf[2][r], sf[3][r]));
#pragma unroll
        for (int off = 1; off < 16; off <<= 1) mt = fmaxf(mt, __shfl_xor(mt, off, 64));
        float mn = fmaxf(m_r[r], mt);
        float alpha = exp2f(m_r[r] - mn);
        float rowsum = 0.f;
#pragma unroll
        for (int j = 0; j < 4; j++) {
          float p = exp2f(sf[j][r] - mn);
          sf[j][r] = p;
          rowsum += p;
        }
#pragma unroll
        for (int off = 1; off < 16; off <<= 1) rowsum += __shfl_xor(rowsum, off, 64);
        l_r[r] = l_r[r] * alpha + rowsum;
        m_r[r] = mn;
#pragma unroll
        for (int jo = 0; jo < 4; jo++) o[jo][r] *= alpha;
      }

      u16* sPw = sP[wave];
#pragma unroll
      for (int j = 0; j < 4; j++)
#pragma unroll
        for (int r = 0; r < 4; r++)
          sPw[(quad * 4 + r) * LP + j * 16 + l16] = f2b(sf[j][r]);
      short8 ap[2];
#pragma unroll
      for (int kk = 0; kk < 2; kk++)
        ap[kk] = *(const short8*)(sPw + l16 * LP + kk * 32 + quad * 8);
#pragma unroll
      for (int jo = 0; jo < 4; jo++)
#pragma unroll
        for (int kk = 0; kk < 2; kk++) {
          short8 bv = *(const short8*)(sV + (jo * 16 + l16) * LP + kk * 32 + quad * 8);
          o[jo] = __builtin_amdgcn_mfma_f32_16x16x32_bf16(ap[kk], bv, o[jo], 0, 0, 0);
        }
    }

#pragma unroll
    for (int r = 0; r < 4; r++) {
      int n = qbase + wave * 16 + quad * 4 + r;
      size_t row = (size_t)bh * N_ + n;
      if (l16 == 0) {
        mlp[2 * (sp * (size_t)65536 + row)]     = m_r[r];
        mlp[2 * (sp * (size_t)65536 + row) + 1] = l_r[r];
      }
#pragma unroll
      for (int jo = 0; jo < 4; jo++)
        opart[sp * (size_t)4194304 + row * 64 + jo * 16 + l16] = f2b(o[jo][r]);
    }
  }
}

// ---------------- combine split-K attn partials -> ob [b,n,h*64+dh] ---------
__global__ __launch_bounds__(256) void attn_combine(const u16* __restrict__ opart,
                                                    const float* __restrict__ mlp,
                                                    u16* __restrict__ obuf) {
  int idx = blockIdx.x * 256 + threadIdx.x;
  int row = idx >> 3, seg = idx & 7;
  float m0 = mlp[2 * row],                 l0 = mlp[2 * row + 1];
  float m1 = mlp[2 * (65536 + row)],       l1 = mlp[2 * (65536 + row) + 1];
  float mmax = fmaxf(m0, m1);
  float w0 = exp2f(m0 - mmax), w1 = exp2f(m1 - mmax);
  float inv = 1.f / (l0 * w0 + l1 * w1);
  short8 a = *(const short8*)(opart + (size_t)row * 64 + seg * 8);
  short8 b = *(const short8*)(opart + (size_t)4194304 + (size_t)row * 64 + seg * 8);
  short8 r;
#pragma unroll
  for (int e = 0; e < 8; e++)
    r[e] = (short)f2b((b2f((u16)a[e]) * w0 + b2f((u16)b[e]) * w1) * inv);
  int bh = row >> 11, n = row & 2047;
  int bb = bh >> 4, h = bh & 15;
  *(short8*)(obuf + ((size_t)(bb * N_ + n) * D_) + h * 64 + seg * 8) = r;
}

extern "C" void kernel_launch(void* const* d_in, const int* in_sizes, int n_in,
                              void* d_out, int out_size, void* d_ws, size_t ws_size,
                              hipStream_t stream) {
  const float* x         = (const float*)d_in[0];
  const float* gamma_pre = (const float*)d_in[1];
  const float* w_qkv     = (const float*)d_in[2];
  const float* w_o       = (const float*)d_in[3];
  const float* gamma_ff  = (const float*)d_in[4];
  const float* w_up      = (const float*)d_in[5];
  const float* b_up      = (const float*)d_in[6];
  const float* w_gate    = (const float*)d_in[7];
  const float* b_gate    = (const float*)d_in[8];
  const float* w_out     = (const float*)d_in[9];
  const float* b_out     = (const float*)d_in[10];
  const float* freqs     = (const float*)d_in[11];
  // d_in[12] = mask, all-True -> no-op in reference; ignored.

  char* ws = (char*)d_ws;
  const size_t MB = 1024 * 1024;
  u16*  h     = (u16*)(ws);              // [0,8)
  u16*  qkv   = (u16*)(ws + 8 * MB);     // [8,32)   dead after rope
  u16*  qr    = (u16*)(ws + 32 * MB);    // [32,40)
  u16*  kr    = (u16*)(ws + 40 * MB);    // [40,48)
  u16*  vtb   = (u16*)(ws + 48 * MB);    // [48,56)
  u16*  ob    = (u16*)(ws + 56 * MB);    // [56,64)  dead after o-proj
  u16*  opart = (u16*)(ws);              // [0,16)   attn partials
  float* mlb  = (float*)(ws + 16 * MB);  // [16,17)  attn m/l
  float* x1   = (float*)(ws + 8 * MB);   // [8,24)   f32
  u16*  h2    = (u16*)(ws + 24 * MB);    // [24,32)  dead after gate gemm
  u16*  up    = (u16*)(ws + 32 * MB);    // [32,64)
  u16*  sp0   = (u16*)(ws);              // [0,8)    split-K partial 0 (8 MB)
  u16*  sp1   = (u16*)(ws + 24 * MB);    // [24,32)  split-K partial 1 (8 MB)
  float* out  = (float*)d_out;

  bool wide = ws_size >= 96 * MB;
  u16* wb_qkv  = (u16*)(ws + 64 * MB);
  u16* wb_o    = (u16*)(ws + 70 * MB);
  u16* wb_up   = (u16*)(ws + 72 * MB);
  u16* wb_gate = (u16*)(ws + 80 * MB);
  u16* wb_out  = (u16*)(ws + 88 * MB);

  if (wide) {
    cvt_kernel<<<(3 * D_ * D_) / 2048, 256, 0, stream>>>(w_qkv, wb_qkv, 3 * D_ * D_);
    cvt_kernel<<<(D_ * D_) / 2048, 256, 0, stream>>>(w_o, wb_o, D_ * D_);
    cvt_kernel<<<(DFF_ * D_) / 2048, 256, 0, stream>>>(w_up, wb_up, DFF_ * D_);
    cvt_kernel<<<(DFF_ * D_) / 2048, 256, 0, stream>>>(w_gate, wb_gate, DFF_ * D_);
    cvt_kernel<<<(DFF_ * D_) / 2048, 256, 0, stream>>>(w_out, wb_out, D_ * DFF_);
  }

  ln_kernel<<<ROWS_, 256, 0, stream>>>(x, gamma_pre, h);
  if (wide)
    gemm_bb<0><<<dim3(3072 / 128, ROWS_ / 128), 256, 0, stream>>>(
        h, wb_qkv, qkv, nullptr, nullptr, ROWS_, 3072, 1024);
  else
    gemm_nt<0><<<dim3(3072 / 128, ROWS_ / 128), 256, 0, stream>>>(
        h, w_qkv, qkv, nullptr, nullptr, ROWS_, 3072, 1024);
  rope_kernel<<<(B_ * N_ * H_ * 32) / 256, 256, 0, stream>>>(qkv, freqs, qr, kr, vtb);
  attn_kernel<<<dim3(N_ / 128, B_ * H_, 2), 256, 0, stream>>>(qr, kr, vtb, opart, mlb);
  attn_combine<<<(B_ * H_ * N_ * 8) / 256, 256, 0, stream>>>(opart, mlb, ob);
  if (wide) {
    // o-proj: split-K x2 (K=1024), partials in dead h/h2 regions
    gemm_bb_split<<<dim3(1024 / 128, ROWS_ / 128, 2), 256, 0, stream>>>(
        ob, wb_o, sp0, sp1, ROWS_, 1024, 1024);
    split_combine<<<(ROWS_ * 1024) / 2048, 256, 0, stream>>>(
        sp0, sp1, nullptr, x, x1, 1024);
    ln_kernel<<<ROWS_, 256, 0, stream>>>(x1, gamma_ff, h2);
    gemm_bb<1><<<dim3(4096 / 128, ROWS_ / 128), 256, 0, stream>>>(
        h2, wb_up, up, b_up, nullptr, ROWS_, 4096, 1024);
    gemm_bb<3><<<dim3(4096 / 128, ROWS_ / 128), 256, 0, stream>>>(
        h2, wb_gate, up, b_gate, up, ROWS_, 4096, 1024);
    // final: split-K x2 (K=4096)
    gemm_bb_split<<<dim3(1024 / 128, ROWS_ / 128, 2), 256, 0, stream>>>(
        up, wb_out, sp0, sp1, ROWS_, 1024, 4096);
    split_combine<<<(ROWS_ * 1024) / 2048, 256, 0, stream>>>(
        sp0, sp1, b_out, x1, out, 1024);
  } else {
    gemm_nt<2><<<dim3(1024 / 128, ROWS_ / 128), 256, 0, stream>>>(
        ob, w_o, x1, nullptr, x, ROWS_, 1024, 1024);
    ln_kernel<<<ROWS_, 256, 0, stream>>>(x1, gamma_ff, h2);
    gemm_nt<1><<<dim3(4096 / 128, ROWS_ / 128), 256, 0, stream>>>(
        h2, w_up, up, b_up, nullptr, ROWS_, 4096, 1024);
    gemm_nt<3><<<dim3(4096 / 128, ROWS_ / 128), 256, 0, stream>>>(
        h2, w_gate, up, b_gate, up, ROWS_, 4096, 1024);
    gemm_nt<4><<<dim3(1024 / 128, ROWS_ / 128), 256, 0, stream>>>(
        up, w_out, (void*)out, b_out, x1, ROWS_, 1024, 4096);
  }
}